// Round 7
// baseline (1910.018 us; speedup 1.0000x reference)
//
#include <hip/hip_runtime.h>
#include <math.h>

#define NN 12288
#define EE 196608
#define NG 8
#define ACH 32   // chunks per graph for adjnew/hout partials
#define GCH 16   // chunks per graph for g2 partials
#define BCAP 64  // bucket capacity per node (deg ~ Poisson(16); P(deg>64) ~ 1e-19/node)
#define APITCH 8256
#define HPITCH 4160
#define GPITCH 1088
#define NBLK 768 // 256 CUs x 3 blocks; __launch_bounds__(256,3) guarantees residency

using short8 = __attribute__((ext_vector_type(8))) short;
using floatx4 = __attribute__((ext_vector_type(4))) float;

__device__ __forceinline__ unsigned short f2bf(float f) {
  union { float f; unsigned u; } v; v.f = f;
  unsigned r = v.u + 0x7FFFu + ((v.u >> 16) & 1u);   // round-to-nearest-even
  return (unsigned short)(r >> 16);
}
__device__ __forceinline__ float bf2f(unsigned short u) {
  union { unsigned u; float f; } v; v.u = ((unsigned)u) << 16;
  return v.f;
}
__device__ __forceinline__ float4 bf2f4(ushort4 u) {
  float4 r; r.x = bf2f(u.x); r.y = bf2f(u.y); r.z = bf2f(u.z); r.w = bf2f(u.w);
  return r;
}

// one-shot global barrier: per-barrier counter (64B apart), zeroed by the
// pre-launch memset each graph replay. Agent-scope atomics + threadfence for
// cross-XCD data visibility (mechanism validated by R4: data flowed correctly
// through 4 grid syncs).
__device__ __forceinline__ void gbar(unsigned* bars, int idx) {
  __threadfence();
  __syncthreads();
  if (threadIdx.x == 0) {
    unsigned* p = bars + idx * 16;
    __hip_atomic_fetch_add(p, 1u, __ATOMIC_ACQ_REL, __HIP_MEMORY_SCOPE_AGENT);
    while (__hip_atomic_load(p, __ATOMIC_ACQUIRE, __HIP_MEMORY_SCOPE_AGENT) < (unsigned)NBLK)
      __builtin_amdgcn_s_sleep(2);
  }
  __syncthreads();
}

// ---------------- persistent mega-kernel: 6 phases, 5 global barriers ----------------
// P0 edge scatter + WTb/bcat/gstart + entropy scalar (1920 units)
// P1 fused dupagg + MFMA gemm + norm + softmax (192 tiles; Zb written and
//    consumed by the same block -> no barrier between the two halves)
// P2 ar gather (3072 units) + dup-sum (48 units)
// P3 big3: role0 hout (256) | role1 adjnew (256) | role2 g2 (128)
// P4 reduce: outa+trace (256) | outh (128) | g2 (32)
// P5 adj_loss scalar (all blocks, idempotent)

__global__ __launch_bounds__(256, 3) void k_mega(
    const int* __restrict__ src, const int* __restrict__ dst, const int* __restrict__ batch,
    const float* __restrict__ x,
    const float* __restrict__ We, const float* __restrict__ be,
    const float* __restrict__ Wp, const float* __restrict__ bp,
    unsigned* cnt_dst, unsigned* cnt_src, int* __restrict__ bdst, int* __restrict__ bsrc,
    unsigned short* __restrict__ WTb, float* __restrict__ bcat, int* __restrict__ gstart,
    unsigned short* __restrict__ Zb, unsigned* __restrict__ dup_part,
    float* __restrict__ embed, unsigned short* __restrict__ Rcb, unsigned short* __restrict__ Arb,
    float* __restrict__ part_h, float* __restrict__ part_adj, float* __restrict__ Gpart,
    double* __restrict__ acc, unsigned* __restrict__ bars, float* __restrict__ out) {
  const int t = threadIdx.x;
  __shared__ __align__(16) char smem[28672];
  float* outa = out;
  float* outh = out + 65536;
  const float4* x4 = (const float4*)x;

  // ---------- P0: edge scatter + setup ----------
  for (int u = blockIdx.x; u < 1920; u += NBLK) {
    unsigned i = (unsigned)u * 256u + (unsigned)t;
    if (i < EE) {
      int s = src[i], d = dst[i];
      unsigned p = atomicAdd(&cnt_dst[d], 1u);
      if (p < BCAP) bdst[(size_t)d * BCAP + p] = s;
    } else if (i < 2u * EE) {
      unsigned e = i - EE;
      int s = src[e], d = dst[e];
      int gd = batch[d];
      unsigned q = atomicAdd(&cnt_src[s], 1u);
      if (q < BCAP) bsrc[(size_t)s * BCAP + q] = (gd << 14) | d;
    } else {
      unsigned j = i - 2u * EE;          // 0..98303
      unsigned n = j >> 8, k = j & 255u;
      float v = (n < 128u) ? We[k * 128u + n] : Wp[k * 256u + (n - 128u)];
      WTb[j] = f2bf(v);
      if (j < 384u) bcat[j] = (j < 128u) ? be[j] : bp[j - 128u];
      if (j <= NG) {   // batch sorted: binary-search graph boundaries
        int g = (int)j, lo = 0, hi = NN;
        while (lo < hi) { int mid = (lo + hi) >> 1; if (batch[mid] < g) lo = mid + 1; else hi = mid; }
        gstart[g] = lo;
      }
    }
  }
  if (blockIdx.x == 0 && t == 0)
    out[98305] = (float)((double)NN * log(32.0));   // entropy: data-independent
  gbar(bars, 0);

  // ---------- P1: fused dupagg (64 nodes) + MFMA gemm + norm + softmax ----------
  for (int u = blockIdx.x; u < 192; u += NBLK) {
    int gm = u * 64;
    int w = t >> 6, lane = t & 63;
    // dupagg: each of 4 waves handles 16 nodes serially
    for (int nl = w; nl < 64; nl += 4) {
      int node = gm + nl;
      unsigned deg = cnt_dst[node];
      unsigned m = deg < BCAP ? deg : BCAP;
      const int* bk = bdst + (size_t)node * BCAP;
      int si = ((unsigned)lane < m) ? bk[lane] : -2;
      unsigned cnt = 0;
      for (unsigned j2 = 0; j2 < m; j2++) {
        int sj = __shfl(si, (int)j2, 64);
        cnt += (si == sj) ? 1u : 0u;
      }
      int h = lane >> 5, c = lane & 31;
      float4 a = {0.f, 0.f, 0.f, 0.f};
      for (unsigned e = (unsigned)h; e < m; e += 2) {
        int sj = __shfl(si, (int)e, 64);
        float4 v = x4[(size_t)sj * 32 + c];
        a.x += v.x; a.y += v.y; a.z += v.z; a.w += v.w;
      }
      a.x += __shfl_xor(a.x, 32, 64);
      a.y += __shfl_xor(a.y, 32, 64);
      a.z += __shfl_xor(a.z, 32, 64);
      a.w += __shfl_xor(a.w, 32, 64);
#pragma unroll
      for (int o = 32; o >= 1; o >>= 1) cnt += __shfl_xor(cnt, o, 64);
      if (lane == 0) dup_part[node] = cnt;
      float inv = 1.f / fmaxf((float)deg, 1.f);
      float4 sv = x4[(size_t)node * 32 + c];
      ushort4 o4;
      if (h == 0) {
        o4.x = f2bf(sv.x); o4.y = f2bf(sv.y); o4.z = f2bf(sv.z); o4.w = f2bf(sv.w);
      } else {
        o4.x = f2bf(a.x * inv); o4.y = f2bf(a.y * inv);
        o4.z = f2bf(a.z * inv); o4.w = f2bf(a.w * inv);
      }
      ((ushort4*)Zb)[(size_t)node * 64 + h * 32 + c] = o4;
    }
    __syncthreads();   // Zb for this tile complete (same block, same CU/L1)

    // gemm + norm + softmax (R6 body)
    unsigned short* Bl = (unsigned short*)smem;            // 24 KB
    unsigned short* Al = (unsigned short*)(smem + 24576);  // 4 KB
    int l = lane;
    floatx4 gacc[24] = {};
    for (int kc = 0; kc < 8; kc++) {
      __syncthreads();
#pragma unroll
      for (int i2 = 0; i2 < 7; i2++) {
        int p = t + i2 * 256;
        if (p < 1536) {
          int n = p >> 2, quad = p & 3;
          uint4 v = *(const uint4*)&WTb[(size_t)n * 256 + kc * 32 + quad * 8];
          *(uint4*)&Bl[(n >> 4) * 512 + ((n & 15) + 16 * quad) * 8] = v;
        } else {
          int p2 = p - 1536;
          int m2 = p2 >> 2, quad = p2 & 3;
          uint4 v = *(const uint4*)&Zb[(size_t)(gm + m2) * 256 + kc * 32 + quad * 8];
          *(uint4*)&Al[(m2 >> 4) * 512 + ((m2 & 15) + 16 * quad) * 8] = v;
        }
      }
      __syncthreads();
      short8 av = *(const short8*)&Al[w * 512 + l * 8];
#pragma unroll
      for (int tt = 0; tt < 24; tt++) {
        short8 bv = *(const short8*)&Bl[tt * 512 + l * 8];
        gacc[tt] = __builtin_amdgcn_mfma_f32_16x16x32_bf16(av, bv, gacc[tt], 0, 0, 0);
      }
    }
    int col16 = l & 15, quad = l >> 4;
#pragma unroll
    for (int tt = 0; tt < 24; tt++) {
      float b = bcat[tt * 16 + col16];
      gacc[tt][0] += b; gacc[tt][1] += b; gacc[tt][2] += b; gacc[tt][3] += b;
    }
#pragma unroll
    for (int r = 0; r < 4; r++) {
      int node = gm + w * 16 + quad * 4 + r;
      float ss = 0.f;
#pragma unroll
      for (int tt = 0; tt < 8; tt++) { float v = gacc[tt][r]; ss += v * v; }
#pragma unroll
      for (int o = 8; o >= 1; o >>= 1) ss += __shfl_xor(ss, o, 64);
      float inv = 1.f / fmaxf(sqrtf(ss), 1e-12f);
#pragma unroll
      for (int tt = 0; tt < 8; tt++)
        embed[(size_t)node * 128 + tt * 16 + col16] = gacc[tt][r] * inv;
      float ss2 = 0.f;
#pragma unroll
      for (int tt = 8; tt < 24; tt++) { float v = gacc[tt][r]; ss2 += v * v; }
#pragma unroll
      for (int o = 8; o >= 1; o >>= 1) ss2 += __shfl_xor(ss2, o, 64);
      float inv2 = 1.f / fmaxf(sqrtf(ss2), 1e-12f);
      int g = batch[node];
      float v0 = 0.f, v1 = 0.f;
#pragma unroll
      for (int tg = 0; tg < 8; tg++) {
        bool sel = (tg == g);
        v0 = sel ? gacc[8 + 2 * tg][r] : v0;
        v1 = sel ? gacc[9 + 2 * tg][r] : v1;
      }
      v0 *= inv2; v1 *= inv2;
      float mx = fmaxf(v0, v1);
#pragma unroll
      for (int o = 8; o >= 1; o >>= 1) mx = fmaxf(mx, __shfl_xor(mx, o, 64));
      float e0 = expf(v0 - mx), e1 = expf(v1 - mx);
      float sm = e0 + e1;
#pragma unroll
      for (int o = 8; o >= 1; o >>= 1) sm += __shfl_xor(sm, o, 64);
      float rr = 1.f / sm;
      Rcb[(size_t)node * 32 + col16] = f2bf(e0 * rr);
      Rcb[(size_t)node * 32 + 16 + col16] = f2bf(e1 * rr);
    }
  }
  gbar(bars, 1);

  // ---------- P2: ar gather (3072) + dup-sum (48) ----------
  for (int u = blockIdx.x; u < 3120; u += NBLK) {
    if (u < 3072) {
      int node = u * 4 + (t >> 6);
      int lane = t & 63;
      int lg = lane >> 3, li = lane & 7;
      unsigned deg = cnt_src[node];
      unsigned m = deg < BCAP ? deg : BCAP;
      const int* bk = bsrc + (size_t)node * BCAP;
      const ushort4* R4 = (const ushort4*)Rcb;
      int pk = ((unsigned)lane < m) ? bk[lane] : (8 << 14);
      float4 a8[8] = {};
#pragma unroll 2
      for (unsigned k = 0; k < m; k += 8) {
        int packed = __shfl(pk, (int)(k + (unsigned)lg), 64);
        int d = packed & 16383, g = packed >> 14;
        float4 r = bf2f4(R4[(size_t)d * 8 + li]);
#pragma unroll
        for (int j = 0; j < 8; j++) {
          float wj = (g == j) ? 1.f : 0.f;
          a8[j].x = fmaf(wj, r.x, a8[j].x);
          a8[j].y = fmaf(wj, r.y, a8[j].y);
          a8[j].z = fmaf(wj, r.z, a8[j].z);
          a8[j].w = fmaf(wj, r.w, a8[j].w);
        }
      }
#pragma unroll
      for (int j = 0; j < 8; j++) {
#pragma unroll
        for (int o = 8; o <= 32; o <<= 1) {
          a8[j].x += __shfl_xor(a8[j].x, o, 64);
          a8[j].y += __shfl_xor(a8[j].y, o, 64);
          a8[j].z += __shfl_xor(a8[j].z, o, 64);
          a8[j].w += __shfl_xor(a8[j].w, o, 64);
        }
      }
      float4 wv = a8[0];
#pragma unroll
      for (int j = 1; j < 8; j++) if (lg == j) wv = a8[j];
      ushort4 ov;
      ov.x = f2bf(wv.x); ov.y = f2bf(wv.y); ov.z = f2bf(wv.z); ov.w = f2bf(wv.w);
      ((ushort4*)Arb)[(size_t)node * 64 + lane] = ov;
    } else {
      int j = (u - 3072) * 256 + t;
      double a2 = (double)dup_part[j];
#pragma unroll
      for (int o = 32; o >= 1; o >>= 1) a2 += __shfl_xor(a2, o, 64);
      if ((t & 63) == 0) atomicAdd(&acc[2], a2);
    }
  }
  gbar(bars, 2);

  // ---------- P3: big3 roles (R6 bodies, bf16 staging) ----------
  for (int u = blockIdx.x; u < 640; u += NBLK) {
    unsigned short* rcs = (unsigned short*)smem;   // 8 KB bf16 staging
    if (u < 256) {           // role0: hout partials
      int g = u >> 5, ch = u & 31;
      int s0 = gstart[g], e0 = gstart[g + 1];
      int per = (e0 - s0 + ACH - 1) / ACH;
      int i0 = s0 + ch * per;
      int i1 = i0 + per; if (i1 > e0) i1 = e0;
      int f4 = t & 31, c1g = t >> 5;
      float4 hacc[4] = {};
      const float4* E4 = (const float4*)embed;
      for (int ib = i0; ib < i1; ib += 64) {
        int cnt = i1 - ib; if (cnt > 64) cnt = 64;
        __syncthreads();
        const ushort4* s4 = (const ushort4*)(Rcb + (size_t)ib * 32);
        for (int idx = t; idx < cnt * 8; idx += 256) ((ushort4*)rcs)[idx] = s4[idx];
        __syncthreads();
        for (int n = 0; n < cnt; n++) {
          float4 e4 = E4[(size_t)(ib + n) * 32 + f4];
          float4 r = bf2f4(*(const ushort4*)&rcs[n * 32 + c1g * 4]);
          float rv[4] = {r.x, r.y, r.z, r.w};
#pragma unroll
          for (int j = 0; j < 4; j++) {
            hacc[j].x += rv[j] * e4.x; hacc[j].y += rv[j] * e4.y;
            hacc[j].z += rv[j] * e4.z; hacc[j].w += rv[j] * e4.w;
          }
        }
      }
      float* p = part_h + (size_t)(g * ACH + ch) * HPITCH;
#pragma unroll
      for (int j = 0; j < 4; j++)
        *(float4*)&p[(c1g * 4 + j) * 128 + f4 * 4] = hacc[j];
    } else if (u < 512) {    // role1: adjnew partials
      int uu = u - 256;
      int g = uu >> 5, ch = uu & 31;
      int s0 = gstart[g], e0 = gstart[g + 1];
      int per = (e0 - s0 + ACH - 1) / ACH;
      int i0 = s0 + ch * per;
      int i1 = i0 + per; if (i1 > e0) i1 = e0;
      int c2q = t & 63, c1g = t >> 6;
      float4 aacc[8] = {};
      const ushort4* Ar4 = (const ushort4*)Arb;
      for (int ib = i0; ib < i1; ib += 64) {
        int cnt = i1 - ib; if (cnt > 64) cnt = 64;
        __syncthreads();
        const ushort4* s4 = (const ushort4*)(Rcb + (size_t)ib * 32);
        for (int idx = t; idx < cnt * 8; idx += 256) ((ushort4*)rcs)[idx] = s4[idx];
        __syncthreads();
        for (int n = 0; n < cnt; n++) {
          float4 a4 = bf2f4(Ar4[(size_t)(ib + n) * 64 + c2q]);
          float4 r0 = bf2f4(*(const ushort4*)&rcs[n * 32 + c1g * 8]);
          float4 r1 = bf2f4(*(const ushort4*)&rcs[n * 32 + c1g * 8 + 4]);
          float rv[8] = {r0.x, r0.y, r0.z, r0.w, r1.x, r1.y, r1.z, r1.w};
#pragma unroll
          for (int j = 0; j < 8; j++) {
            aacc[j].x += rv[j] * a4.x; aacc[j].y += rv[j] * a4.y;
            aacc[j].z += rv[j] * a4.z; aacc[j].w += rv[j] * a4.w;
          }
        }
      }
      float* p = part_adj + (size_t)(g * ACH + ch) * APITCH;
#pragma unroll
      for (int j = 0; j < 8; j++)
        *(float4*)&p[(c1g * 8 + j) * 256 + c2q * 4] = aacc[j];
    } else {                 // role2: g2 partials
      int uu = u - 512;
      int g = uu >> 4, ch = uu & 15;
      int s0 = gstart[g], e0 = gstart[g + 1];
      int per = (e0 - s0 + GCH - 1) / GCH;
      int i0 = s0 + ch * per;
      int i1 = i0 + per; if (i1 > e0) i1 = e0;
      int c2q = t & 7, c1 = t >> 3;
      float4 gacc2 = {};
      for (int ib = i0; ib < i1; ib += 128) {
        int cnt = i1 - ib; if (cnt > 128) cnt = 128;
        __syncthreads();
        const ushort4* s4 = (const ushort4*)(Rcb + (size_t)ib * 32);
        for (int idx = t; idx < cnt * 8; idx += 256) ((ushort4*)rcs)[idx] = s4[idx];
        __syncthreads();
        for (int n = 0; n < cnt; n++) {
          float4 r2 = bf2f4(*(const ushort4*)&rcs[n * 32 + c2q * 4]);
          float r1 = bf2f(rcs[n * 32 + c1]);
          gacc2.x += r1 * r2.x; gacc2.y += r1 * r2.y;
          gacc2.z += r1 * r2.z; gacc2.w += r1 * r2.w;
        }
      }
      *(float4*)&Gpart[(size_t)(g * GCH + ch) * GPITCH + c1 * 32 + c2q * 4] = gacc2;
    }
  }
  gbar(bars, 3);

  // ---------- P4: reduce outa+trace (256) | outh (128) | g2 (32) ----------
  for (int u = blockIdx.x; u < 416; u += NBLK) {
    if (u < 256) {
      int i = u * 256 + t;
      int g = i >> 13, off = i & 8191;
      const float* base = part_adj + (size_t)g * ACH * APITCH + off;
      float s = 0.f;
#pragma unroll
      for (int ch = 0; ch < ACH; ch++) s += base[(size_t)ch * APITCH];
      outa[i] = s;
      if (t == u) atomicAdd(&acc[0], (double)s);   // diagonal
    } else if (u < 384) {
      int j = (u - 256) * 256 + t;
      int g = j >> 12, off = j & 4095;
      const float* base = part_h + (size_t)g * ACH * HPITCH + off;
      float s = 0.f;
#pragma unroll
      for (int ch = 0; ch < ACH; ch++) s += base[(size_t)ch * HPITCH];
      outh[j] = s;
    } else {
      int j = (u - 384) * 256 + t;
      int g = j >> 10, off = j & 1023;
      const float* base = Gpart + (size_t)g * GCH * GPITCH + off;
      float s = 0.f;
#pragma unroll
      for (int ch = 0; ch < GCH; ch++) s += base[(size_t)ch * GPITCH];
      double g2 = (double)s * (double)s;
#pragma unroll
      for (int o = 32; o >= 1; o >>= 1) g2 += __shfl_xor(g2, o, 64);
      if ((t & 63) == 0) atomicAdd(&acc[1], g2);
    }
  }
  gbar(bars, 4);

  // ---------- P5: adj_loss scalar (all blocks, idempotent) ----------
  if (t == 0) {
    double trf = atomicAdd(&acc[0], 0.0);
    double g2f = atomicAdd(&acc[1], 0.0);
    double a2f = atomicAdd(&acc[2], 0.0);
    double val = a2f - 2.0 * trf + g2f;   // ||A - RR^T||_F^2
    if (val < 0.0) val = 0.0;
    out[98304] = (float)(sqrt(val) / ((double)NN * (double)NN));
  }
}

// ---------------- launch ----------------

extern "C" void kernel_launch(void* const* d_in, const int* in_sizes, int n_in,
                              void* d_out, int out_size, void* d_ws, size_t ws_size,
                              hipStream_t stream) {
  const float* x = (const float*)d_in[0];
  const int* ei = (const int*)d_in[1];
  const int* src = ei;
  const int* dst = ei + EE;
  const int* batch = (const int*)d_in[2];
  const float* Wemb = (const float*)d_in[3];
  const float* bemb = (const float*)d_in[4];
  const float* Wpool = (const float*)d_in[5];
  const float* bpool = (const float*)d_in[6];
  float* out = (float*)d_out;

  char* w = (char*)d_ws;
  size_t off = 0;
  auto A = [&](size_t bytes) -> char* {
    char* p = w + off;
    off += (bytes + 255) & ~(size_t)255;
    return p;
  };
  // zero-init region (one memset: counters + acc + barrier slots)
  unsigned* cnt_dst = (unsigned*)A(NN * 4);
  unsigned* cnt_src = (unsigned*)A(NN * 4);
  double* acc = (double*)A(3 * 8);
  unsigned* bars = (unsigned*)A(8 * 16 * 4);   // 8 barrier slots, 64B apart
  size_t zero_bytes = off;
  int* bdst = (int*)A((size_t)NN * BCAP * 4);   // 3.1 MB
  int* bsrc = (int*)A((size_t)NN * BCAP * 4);   // 3.1 MB
  int* gstart = (int*)A(64);
  unsigned* dup_part = (unsigned*)A(NN * 4);
  unsigned short* Zb = (unsigned short*)A((size_t)NN * 256 * 2);  // 6.3 MB bf16
  float* embed = (float*)A((size_t)NN * 128 * 4);                 // 6.3 MB
  unsigned short* Rcb = (unsigned short*)A((size_t)NN * 32 * 2);  // 768 KB bf16
  unsigned short* Arb = (unsigned short*)A((size_t)NN * 256 * 2); // 6.3 MB bf16
  unsigned short* WTb = (unsigned short*)A(384 * 256 * 2);
  float* bcat = (float*)A(384 * 4);
  float* part_h = (float*)A((size_t)8 * ACH * HPITCH * 4);        // 4.3 MB
  float* part_adj = (float*)A((size_t)8 * ACH * APITCH * 4);      // 8.5 MB
  float* Gpart = (float*)A((size_t)8 * GCH * GPITCH * 4);         // 545 KB
  (void)ws_size; (void)in_sizes; (void)n_in; (void)out_size;      // ~40 MB

  hipMemsetAsync(d_ws, 0, zero_bytes, stream);
  k_mega<<<dim3(NBLK), dim3(256), 0, stream>>>(src, dst, batch, x,
      Wemb, bemb, Wpool, bpool, cnt_dst, cnt_src, bdst, bsrc,
      WTb, bcat, gstart, Zb, dup_part, embed, Rcb, Arb,
      part_h, part_adj, Gpart, acc, bars, out);
}

// Round 8
// 170.014 us; speedup vs baseline: 11.2344x; 11.2344x over previous
//
#include <hip/hip_runtime.h>
#include <math.h>

#define NN 12288
#define EE 196608
#define FIN 128
#define AD 256
#define NG 8
#define ACH 32   // chunks per graph for adjnew/hout partials
#define GCH 16   // chunks per graph for g2 partials
#define BCAP 64  // bucket capacity per node (deg ~ Poisson(16); P(deg>64) ~ 1e-19/node)
// partial-chunk pitches padded +64 floats (256 B) to break 32KB power-of-2 stride
// (HBM channel aliasing made k_red3 run at 147 GB/s)
#define APITCH 8256
#define HPITCH 4160
#define GPITCH 1088

using short8 = __attribute__((ext_vector_type(8))) short;
using floatx4 = __attribute__((ext_vector_type(4))) float;

__device__ __forceinline__ unsigned short f2bf(float f) {
  union { float f; unsigned u; } v; v.f = f;
  unsigned r = v.u + 0x7FFFu + ((v.u >> 16) & 1u);   // round-to-nearest-even
  return (unsigned short)(r >> 16);
}

// ---------------- fused edge scatter + setup ----------------
// blocks [0,768): dst-side chain; [768,1536): src-side; [1536,1920): weight
// transpose / bcat / gstart. Counters/acc/done zeroed by hipMemsetAsync.
// bsrc entries pack the dst graph id: (batch[d]<<14)|d  (NN=12288 < 2^14)

__global__ __launch_bounds__(256) void k_edgeB(const int* __restrict__ src, const int* __restrict__ dst,
    const int* __restrict__ batch,
    const float* __restrict__ We, const float* __restrict__ be,
    const float* __restrict__ Wp, const float* __restrict__ bp,
    unsigned* cnt_dst, unsigned* cnt_src, int* __restrict__ bdst, int* __restrict__ bsrc,
    unsigned short* __restrict__ WTb, float* __restrict__ bcat, int* __restrict__ gstart) {
  unsigned i = blockIdx.x * 256u + threadIdx.x;
  if (i < EE) {
    int s = src[i], d = dst[i];
    unsigned p = atomicAdd(&cnt_dst[d], 1u);
    if (p < BCAP) bdst[(size_t)d * BCAP + p] = s;
  } else if (i < 2u * EE) {
    unsigned e = i - EE;
    int s = src[e], d = dst[e];
    int gd = batch[d];
    unsigned q = atomicAdd(&cnt_src[s], 1u);
    if (q < BCAP) bsrc[(size_t)s * BCAP + q] = (gd << 14) | d;
  } else {
    unsigned j = i - 2u * EE;          // 0..98303
    {
      unsigned n = j >> 8, k = j & 255u;
      float v = (n < 128u) ? We[k * 128u + n] : Wp[k * 256u + (n - 128u)];
      WTb[j] = f2bf(v);
    }
    if (j < 384u) bcat[j] = (j < 128u) ? be[j] : bp[j - 128u];
    if (j <= NG) {   // batch sorted: binary-search graph boundaries
      int g = (int)j, lo = 0, hi = NN;
      while (lo < hi) { int mid = (lo + hi) >> 1; if (batch[mid] < g) lo = mid + 1; else hi = mid; }
      gstart[g] = lo;
    }
  }
}

// ---------------- fused: dup-count (||A||^2) + mean aggregation -> Zb bf16 ----------------

__global__ __launch_bounds__(256) void k_dupagg(const float* __restrict__ x,
    const unsigned* __restrict__ cnt_dst, const int* __restrict__ bdst,
    unsigned short* __restrict__ Zb, unsigned* __restrict__ dup_part) {
  int node = blockIdx.x * 4 + (threadIdx.x >> 6);
  int lane = threadIdx.x & 63;
  int h = lane >> 5, c = lane & 31;
  unsigned deg = cnt_dst[node];
  unsigned m = deg < BCAP ? deg : BCAP;   // m <= 64 by construction
  const int* bk = bdst + (size_t)node * BCAP;
  const float4* x4 = (const float4*)x;

  int si = ((unsigned)lane < m) ? bk[lane] : -2;   // sentinel never matches real ids

  unsigned cnt = 0;
  for (unsigned j = 0; j < m; j++) {
    int sj = __shfl(si, (int)j, 64);
    cnt += (si == sj) ? 1u : 0u;
  }

  float4 a = {0.f, 0.f, 0.f, 0.f};
  for (unsigned e = (unsigned)h; e < m; e += 2) {
    int sj = __shfl(si, (int)e, 64);
    float4 v = x4[(size_t)sj * 32 + c];
    a.x += v.x; a.y += v.y; a.z += v.z; a.w += v.w;
  }

  a.x += __shfl_xor(a.x, 32, 64);
  a.y += __shfl_xor(a.y, 32, 64);
  a.z += __shfl_xor(a.z, 32, 64);
  a.w += __shfl_xor(a.w, 32, 64);

#pragma unroll
  for (int o = 32; o >= 1; o >>= 1) cnt += __shfl_xor(cnt, o, 64);
  if (lane == 0) dup_part[node] = cnt;

  float inv = 1.f / fmaxf((float)deg, 1.f);
  float4 sv = x4[(size_t)node * 32 + c];
  ushort4 o4;
  if (h == 0) {
    o4.x = f2bf(sv.x); o4.y = f2bf(sv.y); o4.z = f2bf(sv.z); o4.w = f2bf(sv.w);
  } else {
    o4.x = f2bf(a.x * inv); o4.y = f2bf(a.y * inv);
    o4.z = f2bf(a.z * inv); o4.w = f2bf(a.w * inv);
  }
  ((ushort4*)Zb)[(size_t)node * 64 + h * 32 + c] = o4;
}

// ---------------- fused MFMA GEMM + normalize + block softmax ----------------

__global__ __launch_bounds__(256) void k_gemmnorm(const unsigned short* __restrict__ Zb,
    const unsigned short* __restrict__ WTb, const float* __restrict__ bcat,
    const int* __restrict__ batch, float* __restrict__ embed, float* __restrict__ Rc) {
  __shared__ unsigned short Bl[24 * 512];   // 24 KB
  __shared__ unsigned short Al[4 * 512];    // 4 KB
  int t = threadIdx.x;
  int gm = blockIdx.x * 64;
  int w = t >> 6, l = t & 63;

  floatx4 acc[24] = {};

  for (int kc = 0; kc < 8; kc++) {
    __syncthreads();
#pragma unroll
    for (int i = 0; i < 7; i++) {
      int p = t + i * 256;
      if (p < 1536) {
        int n = p >> 2, quad = p & 3;
        uint4 v = *(const uint4*)&WTb[(size_t)n * 256 + kc * 32 + quad * 8];
        *(uint4*)&Bl[(n >> 4) * 512 + ((n & 15) + 16 * quad) * 8] = v;
      } else {
        int p2 = p - 1536;
        int m = p2 >> 2, quad = p2 & 3;
        uint4 v = *(const uint4*)&Zb[(size_t)(gm + m) * 256 + kc * 32 + quad * 8];
        *(uint4*)&Al[(m >> 4) * 512 + ((m & 15) + 16 * quad) * 8] = v;
      }
    }
    __syncthreads();
    short8 a = *(const short8*)&Al[w * 512 + l * 8];
#pragma unroll
    for (int tt = 0; tt < 24; tt++) {
      short8 b = *(const short8*)&Bl[tt * 512 + l * 8];
      acc[tt] = __builtin_amdgcn_mfma_f32_16x16x32_bf16(a, b, acc[tt], 0, 0, 0);
    }
  }

  int col16 = l & 15, quad = l >> 4;
#pragma unroll
  for (int tt = 0; tt < 24; tt++) {
    float b = bcat[tt * 16 + col16];
    acc[tt][0] += b; acc[tt][1] += b; acc[tt][2] += b; acc[tt][3] += b;
  }

#pragma unroll
  for (int r = 0; r < 4; r++) {
    int node = gm + w * 16 + quad * 4 + r;
    float ss = 0.f;
#pragma unroll
    for (int tt = 0; tt < 8; tt++) { float v = acc[tt][r]; ss += v * v; }
#pragma unroll
    for (int o = 8; o >= 1; o >>= 1) ss += __shfl_xor(ss, o, 64);
    float inv = 1.f / fmaxf(sqrtf(ss), 1e-12f);
#pragma unroll
    for (int tt = 0; tt < 8; tt++)
      embed[(size_t)node * 128 + tt * 16 + col16] = acc[tt][r] * inv;
    float ss2 = 0.f;
#pragma unroll
    for (int tt = 8; tt < 24; tt++) { float v = acc[tt][r]; ss2 += v * v; }
#pragma unroll
    for (int o = 8; o >= 1; o >>= 1) ss2 += __shfl_xor(ss2, o, 64);
    float inv2 = 1.f / fmaxf(sqrtf(ss2), 1e-12f);
    int g = batch[node];
    float v0 = 0.f, v1 = 0.f;
#pragma unroll
    for (int tg = 0; tg < 8; tg++) {
      bool sel = (tg == g);
      v0 = sel ? acc[8 + 2 * tg][r] : v0;
      v1 = sel ? acc[9 + 2 * tg][r] : v1;
    }
    v0 *= inv2; v1 *= inv2;
    float mx = fmaxf(v0, v1);
#pragma unroll
    for (int o = 8; o >= 1; o >>= 1) mx = fmaxf(mx, __shfl_xor(mx, o, 64));
    float e0 = expf(v0 - mx), e1 = expf(v1 - mx);
    float sm = e0 + e1;
#pragma unroll
    for (int o = 8; o >= 1; o >>= 1) sm += __shfl_xor(sm, o, 64);
    float rr = 1.f / sm;
    Rc[(size_t)node * 32 + col16] = e0 * rr;
    Rc[(size_t)node * 32 + 16 + col16] = e1 * rr;
  }
}

// ---------------- Ar[i,:] = sum over out-edges of R[dst,:] (src buckets, packed g) ----------------
// 8 edges/iteration: lane-group lg (8 lanes) owns edge k+lg, loads the dst row's
// 32-float block (full 1 KB/wave/iter), accumulates into 8 statically-indexed
// per-graph accumulators (branchless select), shfl_xor group-combine at the end.

__global__ __launch_bounds__(256) void k_ar(const float* __restrict__ Rc,
    const unsigned* __restrict__ cnt_src, const int* __restrict__ bsrc,
    float* __restrict__ Ar) {
  int node = blockIdx.x * 4 + (threadIdx.x >> 6);
  int lane = threadIdx.x & 63;
  int lg = lane >> 3, li = lane & 7;
  unsigned deg = cnt_src[node];
  unsigned m = deg < BCAP ? deg : BCAP;   // m <= 64 by construction
  const int* bk = bsrc + (size_t)node * BCAP;
  const float4* R4 = (const float4*)Rc;

  // sentinel: g=8 (matches no j), d=0 (valid address, never accumulated)
  int pk = ((unsigned)lane < m) ? bk[lane] : (8 << 14);

  float4 acc[8] = {};
#pragma unroll 2
  for (unsigned k = 0; k < m; k += 8) {
    int packed = __shfl(pk, (int)(k + (unsigned)lg), 64);
    int d = packed & 16383, g = packed >> 14;
    float4 r = R4[(size_t)d * 8 + li];
#pragma unroll
    for (int j = 0; j < 8; j++) {
      float wj = (g == j) ? 1.f : 0.f;
      acc[j].x = fmaf(wj, r.x, acc[j].x);
      acc[j].y = fmaf(wj, r.y, acc[j].y);
      acc[j].z = fmaf(wj, r.z, acc[j].z);
      acc[j].w = fmaf(wj, r.w, acc[j].w);
    }
  }

  // combine the 8 lane-groups (lg spans lane bits 3..5)
#pragma unroll
  for (int j = 0; j < 8; j++) {
#pragma unroll
    for (int o = 8; o <= 32; o <<= 1) {
      acc[j].x += __shfl_xor(acc[j].x, o, 64);
      acc[j].y += __shfl_xor(acc[j].y, o, 64);
      acc[j].z += __shfl_xor(acc[j].z, o, 64);
      acc[j].w += __shfl_xor(acc[j].w, o, 64);
    }
  }
  float4 wv = acc[0];
#pragma unroll
  for (int j = 1; j < 8; j++) if (lg == j) wv = acc[j];
  ((float4*)Ar)[(size_t)node * 64 + lane] = wv;
}

// ---------------- fused R^T-GEMM partials: role 0 = hout, 1 = adjnew, 2 = g2 ----------------

__global__ __launch_bounds__(256) void k_big3(const float* __restrict__ Rc,
    const float* __restrict__ embed, const float* __restrict__ Ar, const int* __restrict__ gstart,
    float* __restrict__ part_h, float* __restrict__ part_adj, float* __restrict__ Gpart) {
  int role = blockIdx.z;
  int g = blockIdx.x, ch = blockIdx.y;
  if (role == 2 && ch >= GCH) return;
  int s0 = gstart[g], e0 = gstart[g + 1];
  int nch = (role == 2) ? GCH : ACH;
  int per = (e0 - s0 + nch - 1) / nch;
  int i0 = s0 + ch * per;
  int i1 = i0 + per; if (i1 > e0) i1 = e0;
  int t = threadIdx.x;
  __shared__ float rcs[128][32];   // 16 KB; roles 0/1 use first 64 rows

  if (role == 0) {
    int f4 = t & 31, c1g = t >> 5;
    float4 acc[4] = {};
    const float4* E4 = (const float4*)embed;
    for (int ib = i0; ib < i1; ib += 64) {
      int cnt = i1 - ib; if (cnt > 64) cnt = 64;
      __syncthreads();
      const float4* s4 = (const float4*)(Rc + (size_t)ib * 32);
      for (int idx = t; idx < cnt * 8; idx += 256) ((float4*)rcs)[idx] = s4[idx];
      __syncthreads();
      for (int n = 0; n < cnt; n++) {
        float4 e4 = E4[(size_t)(ib + n) * 32 + f4];
        float4 r = *(const float4*)&rcs[n][c1g * 4];
        float rv[4] = {r.x, r.y, r.z, r.w};
#pragma unroll
        for (int j = 0; j < 4; j++) {
          acc[j].x += rv[j] * e4.x; acc[j].y += rv[j] * e4.y;
          acc[j].z += rv[j] * e4.z; acc[j].w += rv[j] * e4.w;
        }
      }
    }
    float* p = part_h + (size_t)(g * ACH + ch) * HPITCH;
#pragma unroll
    for (int j = 0; j < 4; j++)
      *(float4*)&p[(c1g * 4 + j) * 128 + f4 * 4] = acc[j];
  } else if (role == 1) {
    int c2q = t & 63, c1g = t >> 6;
    float4 acc[8] = {};
    const float4* Ar4 = (const float4*)Ar;
    for (int ib = i0; ib < i1; ib += 64) {
      int cnt = i1 - ib; if (cnt > 64) cnt = 64;
      __syncthreads();
      const float4* s4 = (const float4*)(Rc + (size_t)ib * 32);
      for (int idx = t; idx < cnt * 8; idx += 256) ((float4*)rcs)[idx] = s4[idx];
      __syncthreads();
      for (int n = 0; n < cnt; n++) {
        float4 a4 = Ar4[(size_t)(ib + n) * 64 + c2q];
        float4 r0 = *(const float4*)&rcs[n][c1g * 8];
        float4 r1 = *(const float4*)&rcs[n][c1g * 8 + 4];
        float rv[8] = {r0.x, r0.y, r0.z, r0.w, r1.x, r1.y, r1.z, r1.w};
#pragma unroll
        for (int j = 0; j < 8; j++) {
          acc[j].x += rv[j] * a4.x; acc[j].y += rv[j] * a4.y;
          acc[j].z += rv[j] * a4.z; acc[j].w += rv[j] * a4.w;
        }
      }
    }
    float* p = part_adj + (size_t)(g * ACH + ch) * APITCH;
#pragma unroll
    for (int j = 0; j < 8; j++)
      *(float4*)&p[(c1g * 8 + j) * 256 + c2q * 4] = acc[j];
  } else {
    int c2q = t & 7, c1 = t >> 3;
    float4 acc = {};
    for (int ib = i0; ib < i1; ib += 128) {
      int cnt = i1 - ib; if (cnt > 128) cnt = 128;
      __syncthreads();
      const float4* s4 = (const float4*)(Rc + (size_t)ib * 32);
      for (int idx = t; idx < cnt * 8; idx += 256) ((float4*)rcs)[idx] = s4[idx];
      __syncthreads();
      for (int n = 0; n < cnt; n++) {
        float4 r2 = *(const float4*)&rcs[n][c2q * 4];
        float r1 = rcs[n][c1];
        acc.x += r1 * r2.x; acc.y += r1 * r2.y; acc.z += r1 * r2.z; acc.w += r1 * r2.w;
      }
    }
    *(float4*)&Gpart[(size_t)(g * GCH + ch) * GPITCH + c1 * 32 + c2q * 4] = acc;
  }
}

// ---------------- fused reduce + loss scalars (last-block finalize) ----------------

__global__ __launch_bounds__(256) void k_red3(const float* __restrict__ part_adj,
    const float* __restrict__ part_h, const float* __restrict__ Gpart,
    const unsigned* __restrict__ dup_part,
    float* __restrict__ outa, float* __restrict__ outh,
    double* __restrict__ acc, unsigned* __restrict__ done, float* __restrict__ out) {
  int b = blockIdx.x, t = threadIdx.x;
  int lane = t & 63;
  if (b < 256) {
    int i = b * 256 + t;
    int g = i >> 13, off = i & 8191;
    const float* base = part_adj + (size_t)g * ACH * APITCH + off;
    float s = 0.f;
#pragma unroll
    for (int ch = 0; ch < ACH; ch++) s += base[(size_t)ch * APITCH];
    outa[i] = s;
    if (t == b) atomicAdd(&acc[0], (double)s);   // row b, col t: diagonal
  } else if (b < 384) {
    int j = (b - 256) * 256 + t;
    int g = j >> 12, off = j & 4095;
    const float* base = part_h + (size_t)g * ACH * HPITCH + off;
    float s = 0.f;
#pragma unroll
    for (int ch = 0; ch < ACH; ch++) s += base[(size_t)ch * HPITCH];
    outh[j] = s;
  } else if (b < 416) {
    int j = (b - 384) * 256 + t;
    int g = j >> 10, off = j & 1023;
    const float* base = Gpart + (size_t)g * GCH * GPITCH + off;
    float s = 0.f;
#pragma unroll
    for (int ch = 0; ch < GCH; ch++) s += base[(size_t)ch * GPITCH];
    double g2 = (double)s * (double)s;
#pragma unroll
    for (int o = 32; o >= 1; o >>= 1) g2 += __shfl_xor(g2, o, 64);
    if (lane == 0) atomicAdd(&acc[1], g2);
  } else {
    int j = (b - 416) * 256 + t;
    double a2 = (double)dup_part[j];
#pragma unroll
    for (int o = 32; o >= 1; o >>= 1) a2 += __shfl_xor(a2, o, 64);
    if (lane == 0) atomicAdd(&acc[2], a2);
  }
  __syncthreads();   // drains vmcnt: this block's atomics are globally performed
  if (t == 0) {
    unsigned prev = atomicAdd(done, 1u);
    if (prev == gridDim.x - 1) {
      double trf = atomicAdd(&acc[0], 0.0);
      double g2f = atomicAdd(&acc[1], 0.0);
      double a2f = atomicAdd(&acc[2], 0.0);
      double val = a2f - 2.0 * trf + g2f;   // ||A - RR^T||_F^2
      if (val < 0.0) val = 0.0;
      out[98304] = (float)(sqrt(val) / ((double)NN * (double)NN));
      out[98305] = (float)((double)NN * log(32.0));
    }
  }
}

// ---------------- launch ----------------

extern "C" void kernel_launch(void* const* d_in, const int* in_sizes, int n_in,
                              void* d_out, int out_size, void* d_ws, size_t ws_size,
                              hipStream_t stream) {
  const float* x = (const float*)d_in[0];
  const int* ei = (const int*)d_in[1];
  const int* src = ei;
  const int* dst = ei + EE;
  const int* batch = (const int*)d_in[2];
  const float* Wemb = (const float*)d_in[3];
  const float* bemb = (const float*)d_in[4];
  const float* Wpool = (const float*)d_in[5];
  const float* bpool = (const float*)d_in[6];
  float* out = (float*)d_out;

  char* w = (char*)d_ws;
  size_t off = 0;
  auto A = [&](size_t bytes) -> char* {
    char* p = w + off;
    off += (bytes + 255) & ~(size_t)255;
    return p;
  };
  // zero-init region first (one memset: counters + acc + done)
  unsigned* cnt_dst = (unsigned*)A(NN * 4);
  unsigned* cnt_src = (unsigned*)A(NN * 4);
  double* acc = (double*)A(3 * 8);
  unsigned* done = (unsigned*)A(4);
  size_t zero_bytes = off;
  int* bdst = (int*)A((size_t)NN * BCAP * 4);   // 3.1 MB
  int* bsrc = (int*)A((size_t)NN * BCAP * 4);   // 3.1 MB
  int* gstart = (int*)A(64);
  unsigned* dup_part = (unsigned*)A(NN * 4);
  unsigned short* Zb = (unsigned short*)A((size_t)NN * 256 * 2);  // 6.3 MB bf16
  float* embed = (float*)A((size_t)NN * FIN * 4);                 // 6.3 MB
  float* Rc = (float*)A((size_t)NN * 32 * 4);                     // 1.6 MB
  float* Ar = (float*)A((size_t)NN * AD * 4);                     // 12.6 MB
  unsigned short* WTb = (unsigned short*)A(384 * 256 * 2);
  float* bcat = (float*)A(384 * 4);
  float* part_h = (float*)A((size_t)8 * ACH * HPITCH * 4);        // 4.3 MB
  float* part_adj = (float*)A((size_t)8 * ACH * APITCH * 4);      // 8.5 MB
  float* Gpart = (float*)A((size_t)8 * GCH * GPITCH * 4);         // 545 KB
  (void)ws_size; (void)in_sizes; (void)n_in; (void)out_size;      // ~47 MB

  hipMemsetAsync(d_ws, 0, zero_bytes, stream);
  k_edgeB<<<dim3(2 * EE / 256 + 384), dim3(256), 0, stream>>>(src, dst, batch,
      Wemb, bemb, Wpool, bpool, cnt_dst, cnt_src, bdst, bsrc, WTb, bcat, gstart);
  k_dupagg<<<dim3(NN / 4), dim3(256), 0, stream>>>(x, cnt_dst, bdst, Zb, dup_part);
  k_gemmnorm<<<dim3(NN / 64), dim3(256), 0, stream>>>(Zb, WTb, bcat, batch, embed, Rc);
  k_ar<<<dim3(NN / 4), dim3(256), 0, stream>>>(Rc, cnt_src, bsrc, Ar);
  k_big3<<<dim3(8, ACH, 3), dim3(256), 0, stream>>>(Rc, embed, Ar, gstart, part_h, part_adj, Gpart);
  k_red3<<<dim3(464), dim3(256), 0, stream>>>(part_adj, part_h, Gpart, dup_part,
      out, out + 65536, acc, done, out);
}